// Round 1
// baseline (186.119 us; speedup 1.0000x reference)
//
#include <hip/hip_runtime.h>
#include <hip/hip_bf16.h>
#include <math.h>

// Problem: B=16, T=2048, D=256, gamma=0.9
// out[b,t,d] = S2[t,d] * (x@Wq)[b,t,d]
// S2[t,d] = S[8d + (t>>8)][t&255]
// S[t>=1] = A[t], S[0] = A[1],  A[t] = gamma*A[t-1] + g[t], A[0]=0 (g[0] := 0)
// g = y @ Wk,  y[t,:] = sum_b w[b,t]*x[b,t,:],  w[b,t] = x[b,t,:] . rowsum(Wv)

#define GAMMA_F 0.9f
#define T_LEN 2048
#define D_DIM 256
#define B_DIM 16
#define NCHUNK 32
#define CHUNK 64

// ---------- K1: wv_sum[j] = sum_d Wv[j][d] ----------
__global__ void k_wvsum(const float* __restrict__ Wv, float* __restrict__ wv_sum) {
    int j = blockIdx.x;      // 0..255
    int l = threadIdx.x;     // 0..63
    const float* row = Wv + (size_t)j * D_DIM;
    float s = row[l] + row[l + 64] + row[l + 128] + row[l + 192];
    for (int o = 32; o > 0; o >>= 1) s += __shfl_down(s, o, 64);
    if (l == 0) wv_sum[j] = s;
}

// ---------- K2: y[t][d] = sum_b (x[b,t,:].wv_sum) * x[b,t,d] ----------
__global__ __launch_bounds__(256) void k_y(const float* __restrict__ x,
                                           const float* __restrict__ wv_sum,
                                           float* __restrict__ y) {
    int t = blockIdx.x;      // 0..2047
    int d = threadIdx.x;     // 0..255
    float wvd = wv_sum[d];
    float xr[B_DIM];
#pragma unroll
    for (int b = 0; b < B_DIM; ++b)
        xr[b] = x[((size_t)b * T_LEN + t) * D_DIM + d];

    __shared__ float red[B_DIM][4];
    int wave = d >> 6, lane = d & 63;
#pragma unroll
    for (int b = 0; b < B_DIM; ++b) {
        float p = xr[b] * wvd;
        for (int o = 32; o > 0; o >>= 1) p += __shfl_down(p, o, 64);
        if (lane == 0) red[b][wave] = p;
    }
    __syncthreads();
    float yv = 0.f;
#pragma unroll
    for (int b = 0; b < B_DIM; ++b) {
        float wb = red[b][0] + red[b][1] + red[b][2] + red[b][3];
        yv += wb * xr[b];
    }
    y[(size_t)t * D_DIM + d] = yv;
}

// ---------- K3: g = y @ Wk   (M-tile = 8) ----------
__global__ __launch_bounds__(256) void k_g(const float* __restrict__ y,
                                           const float* __restrict__ Wk,
                                           float* __restrict__ g) {
    int t0 = blockIdx.x * 8;
    int d = threadIdx.x;
    __shared__ float ys[8][D_DIM];
    const float4* yg = (const float4*)(y + (size_t)t0 * D_DIM);
    float4* ysv = (float4*)ys;
    ysv[d] = yg[d];
    ysv[d + 256] = yg[d + 256];
    __syncthreads();
    float acc[8];
#pragma unroll
    for (int r = 0; r < 8; ++r) acc[r] = 0.f;
    for (int k4 = 0; k4 < 64; ++k4) {
        float wk0 = Wk[(size_t)(k4 * 4 + 0) * D_DIM + d];
        float wk1 = Wk[(size_t)(k4 * 4 + 1) * D_DIM + d];
        float wk2 = Wk[(size_t)(k4 * 4 + 2) * D_DIM + d];
        float wk3 = Wk[(size_t)(k4 * 4 + 3) * D_DIM + d];
#pragma unroll
        for (int r = 0; r < 8; ++r) {
            float4 yv = *(const float4*)&ys[r][k4 * 4];
            acc[r] += yv.x * wk0 + yv.y * wk1 + yv.z * wk2 + yv.w * wk3;
        }
    }
#pragma unroll
    for (int r = 0; r < 8; ++r) g[(size_t)(t0 + r) * D_DIM + d] = acc[r];
}

// ---------- K4: per-chunk local scan ----------
__global__ void k_scanA(const float* __restrict__ g, float* __restrict__ loc,
                        float* __restrict__ carry) {
    int c = blockIdx.x;      // 0..31
    int d = threadIdx.x;     // 0..255
    float acc = 0.f;
    int base = c * CHUNK;
    for (int o = 0; o < CHUNK; ++o) {
        int t = base + o;
        float gv = (t == 0) ? 0.f : g[(size_t)t * D_DIM + d];
        acc = GAMMA_F * acc + gv;
        loc[(size_t)t * D_DIM + d] = acc;
    }
    carry[(size_t)c * D_DIM + d] = acc;
}

// ---------- K5: sequential carry prefix P[c] = A[64c-1] ----------
__global__ void k_scanB(const float* __restrict__ carry, float* __restrict__ P) {
    int d = threadIdx.x;     // 0..255
    float g64 = powf(GAMMA_F, 64.0f);
    float p = 0.f;
    P[d] = 0.f;
    for (int c = 1; c < NCHUNK; ++c) {
        p = carry[(size_t)(c - 1) * D_DIM + d] + g64 * p;
        P[(size_t)c * D_DIM + d] = p;
    }
}

// ---------- K6: A[t] = loc[t] + gamma^(o+1)*P[c]; scatter into S2 ----------
__global__ __launch_bounds__(256) void k_S2(const float* __restrict__ loc,
                                            const float* __restrict__ P,
                                            float* __restrict__ S2) {
    int tp = blockIdx.x;     // S row index t' = 0..2047
    int r = threadIdx.x;     // 0..255
    int src = (tp == 0) ? 1 : tp;           // S[0] = A[1]
    int c = src >> 6, o = src & 63;
    float gp = powf(GAMMA_F, (float)(o + 1));
    float Aval = loc[(size_t)src * D_DIM + r] + gp * P[(size_t)c * D_DIM + r];
    // S[t'][r] -> S2[256*(t'&7) + r][t'>>3]
    int trow = ((tp & 7) << 8) + r;
    int dcol = tp >> 3;
    S2[(size_t)trow * D_DIM + dcol] = Aval;
}

// ---------- K7: out = (x @ Wq) * S2 (broadcast over batch) ----------
// M-tile = 64 rows, 256 threads: thread = (rowgroup = tid>>6 -> 16 rows, colgroup = tid&63 -> 4 cols)
__global__ __launch_bounds__(256) void k_qgemm(const float* __restrict__ x,
                                               const float* __restrict__ Wq,
                                               const float* __restrict__ S2,
                                               float* __restrict__ out) {
    __shared__ float xs[64][D_DIM];   // 64 KB
    int bt0 = blockIdx.x * 64;
    int tid = threadIdx.x;
    const float4* xg = (const float4*)(x + (size_t)bt0 * D_DIM);
    float4* xsv = (float4*)xs;
#pragma unroll
    for (int i = 0; i < 16; ++i) xsv[tid + 256 * i] = xg[tid + 256 * i];
    __syncthreads();

    int c4 = (tid & 63) * 4;          // column base
    int r0 = (tid >> 6) * 16;         // row base within tile
    float4 acc[16];
#pragma unroll
    for (int r = 0; r < 16; ++r) acc[r] = make_float4(0.f, 0.f, 0.f, 0.f);

    for (int k4 = 0; k4 < 64; ++k4) {
        float4 wq0 = *(const float4*)(Wq + (size_t)(k4 * 4 + 0) * D_DIM + c4);
        float4 wq1 = *(const float4*)(Wq + (size_t)(k4 * 4 + 1) * D_DIM + c4);
        float4 wq2 = *(const float4*)(Wq + (size_t)(k4 * 4 + 2) * D_DIM + c4);
        float4 wq3 = *(const float4*)(Wq + (size_t)(k4 * 4 + 3) * D_DIM + c4);
#pragma unroll
        for (int r = 0; r < 16; ++r) {
            float4 xv = *(const float4*)&xs[r0 + r][k4 * 4];
            acc[r].x += xv.x * wq0.x + xv.y * wq1.x + xv.z * wq2.x + xv.w * wq3.x;
            acc[r].y += xv.x * wq0.y + xv.y * wq1.y + xv.z * wq2.y + xv.w * wq3.y;
            acc[r].z += xv.x * wq0.z + xv.y * wq1.z + xv.z * wq2.z + xv.w * wq3.z;
            acc[r].w += xv.x * wq0.w + xv.y * wq1.w + xv.z * wq2.w + xv.w * wq3.w;
        }
    }

    int t0 = (bt0 & (T_LEN - 1)) + r0;   // t index (same b across tile)
#pragma unroll
    for (int r = 0; r < 16; ++r) {
        float4 s2 = *(const float4*)(S2 + (size_t)(t0 + r) * D_DIM + c4);
        float4 a = acc[r];
        a.x *= s2.x; a.y *= s2.y; a.z *= s2.z; a.w *= s2.w;
        *(float4*)(out + (size_t)(bt0 + r0 + r) * D_DIM + c4) = a;
    }
}

extern "C" void kernel_launch(void* const* d_in, const int* in_sizes, int n_in,
                              void* d_out, int out_size, void* d_ws, size_t ws_size,
                              hipStream_t stream) {
    const float* x  = (const float*)d_in[0];
    const float* Wq = (const float*)d_in[1];
    const float* Wk = (const float*)d_in[2];
    const float* Wv = (const float*)d_in[3];
    float* out = (float*)d_out;

    // workspace layout (floats)
    float* ws = (float*)d_ws;
    float* y      = ws;                       // 2048*256
    float* g      = y + 524288;               // 2048*256
    float* loc    = g + 524288;               // 2048*256
    float* S2     = loc + 524288;             // 2048*256
    float* wv_sum = S2 + 524288;              // 256
    float* carry  = wv_sum + 256;             // 32*256
    float* P      = carry + 8192;             // 32*256

    k_wvsum<<<256, 64, 0, stream>>>(Wv, wv_sum);
    k_y<<<T_LEN, 256, 0, stream>>>(x, wv_sum, y);
    k_g<<<T_LEN / 8, 256, 0, stream>>>(y, Wk, g);
    k_scanA<<<NCHUNK, 256, 0, stream>>>(g, loc, carry);
    k_scanB<<<1, 256, 0, stream>>>(carry, P);
    k_S2<<<T_LEN, 256, 0, stream>>>(loc, P, S2);
    k_qgemm<<<(B_DIM * T_LEN) / 64, 256, 0, stream>>>(x, Wq, S2, out);
}

// Round 2
// 146.802 us; speedup vs baseline: 1.2678x; 1.2678x over previous
//
#include <hip/hip_runtime.h>
#include <hip/hip_bf16.h>
#include <math.h>

// Problem: B=16, T=2048, D=256, gamma=0.9
// out[b,t,d] = S2[t,d] * (x@Wq)[b,t,d]
// S2[t,d] = S[8d + (t>>8)][t&255]   (reshape-scramble)
// S[t>=1] = A[t], S[0] = A[1],  A[t] = gamma*A[t-1] + g[t], A[0]=0 (g[0] := 0)
// g = y @ Wk,  y[t,:] = sum_b w[b,t]*x[b,t,:],  w[b,t] = x[b,t,:] . rowsum(Wv)

#define GAMMA_F 0.9f
#define T_LEN 2048
#define D_DIM 256
#define B_DIM 16
#define NCHUNK 32
#define CHUNK 64

typedef __attribute__((ext_vector_type(8))) short bf16x8;
typedef __attribute__((ext_vector_type(16))) float f32x16;

__device__ inline ushort f2bf(float f) {
    union { float f; unsigned u; } v; v.f = f;
    unsigned r = (v.u + 0x7FFFu + ((v.u >> 16) & 1u)) >> 16;  // RNE
    return (ushort)r;
}

// ---------- K1: wv_sum[j] = sum_d Wv[j][d] ----------
__global__ void k_wvsum(const float* __restrict__ Wv, float* __restrict__ wv_sum) {
    int j = blockIdx.x;      // 0..255
    int l = threadIdx.x;     // 0..63
    const float* row = Wv + (size_t)j * D_DIM;
    float s = row[l] + row[l + 64] + row[l + 128] + row[l + 192];
    for (int o = 32; o > 0; o >>= 1) s += __shfl_down(s, o, 64);
    if (l == 0) wv_sum[j] = s;
}

// ---------- K2: WqT[n][k] = bf16(Wq[k][n]) ----------
__global__ __launch_bounds__(256) void k_wqT(const float* __restrict__ Wq,
                                             ushort* __restrict__ WqT) {
    __shared__ float tile[64][68];
    int k0 = (blockIdx.x & 3) * 64;
    int n0 = (blockIdx.x >> 2) * 64;
    int tid = threadIdx.x;
    int r = tid >> 4;            // 0..15
    int c4 = (tid & 15) * 4;     // 0..60
#pragma unroll
    for (int i = 0; i < 4; ++i) {
        float4 v = *(const float4*)(Wq + (size_t)(k0 + r + 16 * i) * D_DIM + n0 + c4);
        *(float4*)&tile[r + 16 * i][c4] = v;
    }
    __syncthreads();
    int n = tid >> 2;            // 0..63
    int j0 = (tid & 3) * 16;     // 0..48
    ushort tmp[16];
#pragma unroll
    for (int i = 0; i < 16; ++i) tmp[i] = f2bf(tile[j0 + i][n]);
    ushort* dst = WqT + (size_t)(n0 + n) * D_DIM + k0 + j0;
#pragma unroll
    for (int i = 0; i < 16; ++i) dst[i] = tmp[i];
}

// ---------- K3: y[t][d] = sum_b (x[b,t,:].wv_sum) * x[b,t,d] ----------
__global__ __launch_bounds__(256) void k_y(const float* __restrict__ x,
                                           const float* __restrict__ wv_sum,
                                           float* __restrict__ y) {
    int t = blockIdx.x;      // 0..2047
    int d = threadIdx.x;     // 0..255
    float wvd = wv_sum[d];
    float xr[B_DIM];
#pragma unroll
    for (int b = 0; b < B_DIM; ++b)
        xr[b] = x[((size_t)b * T_LEN + t) * D_DIM + d];

    __shared__ float red[B_DIM][4];
    int wave = d >> 6, lane = d & 63;
#pragma unroll
    for (int b = 0; b < B_DIM; ++b) {
        float p = xr[b] * wvd;
        for (int o = 32; o > 0; o >>= 1) p += __shfl_down(p, o, 64);
        if (lane == 0) red[b][wave] = p;
    }
    __syncthreads();
    float yv = 0.f;
#pragma unroll
    for (int b = 0; b < B_DIM; ++b) {
        float wb = red[b][0] + red[b][1] + red[b][2] + red[b][3];
        yv += wb * xr[b];
    }
    y[(size_t)t * D_DIM + d] = yv;
}

// ---------- K4: g = y @ Wk   (M-tile = 8) ----------
__global__ __launch_bounds__(256) void k_g(const float* __restrict__ y,
                                           const float* __restrict__ Wk,
                                           float* __restrict__ g) {
    int t0 = blockIdx.x * 8;
    int d = threadIdx.x;
    __shared__ float ys[8][D_DIM];
    const float4* yg = (const float4*)(y + (size_t)t0 * D_DIM);
    float4* ysv = (float4*)ys;
    ysv[d] = yg[d];
    ysv[d + 256] = yg[d + 256];
    __syncthreads();
    float acc[8];
#pragma unroll
    for (int r = 0; r < 8; ++r) acc[r] = 0.f;
    for (int k4 = 0; k4 < 64; ++k4) {
        float wk0 = Wk[(size_t)(k4 * 4 + 0) * D_DIM + d];
        float wk1 = Wk[(size_t)(k4 * 4 + 1) * D_DIM + d];
        float wk2 = Wk[(size_t)(k4 * 4 + 2) * D_DIM + d];
        float wk3 = Wk[(size_t)(k4 * 4 + 3) * D_DIM + d];
#pragma unroll
        for (int r = 0; r < 8; ++r) {
            float4 yv = *(const float4*)&ys[r][k4 * 4];
            acc[r] += yv.x * wk0 + yv.y * wk1 + yv.z * wk2 + yv.w * wk3;
        }
    }
#pragma unroll
    for (int r = 0; r < 8; ++r) g[(size_t)(t0 + r) * D_DIM + d] = acc[r];
}

// ---------- K5: per-chunk local scan ----------
__global__ void k_scanA(const float* __restrict__ g, float* __restrict__ loc,
                        float* __restrict__ carry) {
    int c = blockIdx.x;      // 0..31
    int d = threadIdx.x;     // 0..255
    float acc = 0.f;
    int base = c * CHUNK;
    for (int o = 0; o < CHUNK; ++o) {
        int t = base + o;
        float gv = (t == 0) ? 0.f : g[(size_t)t * D_DIM + d];
        acc = GAMMA_F * acc + gv;
        loc[(size_t)t * D_DIM + d] = acc;
    }
    carry[(size_t)c * D_DIM + d] = acc;
}

// ---------- K6: A[t] = loc[t] + gamma^(o+1)*P[c]; P computed inline; scatter ----------
__global__ __launch_bounds__(256) void k_S2P(const float* __restrict__ loc,
                                             const float* __restrict__ carry,
                                             float* __restrict__ S2) {
    int tp = blockIdx.x;     // S row index t' = 0..2047
    int r = threadIdx.x;     // 0..255
    int src = (tp == 0) ? 1 : tp;           // S[0] = A[1]
    int c = src >> 6, o = src & 63;
    const float g64 = 1.1790184577738601e-03f;  // 0.9^64
    // P[c] = sum_{j<c} g64^(c-1-j) * carry[j]  (parallel weighted sum)
    float p = 0.f;
    for (int j = 0; j < c; ++j)
        p = p * g64 + carry[(size_t)j * D_DIM + r];
    float gp = powf(GAMMA_F, (float)(o + 1));
    float Aval = loc[(size_t)src * D_DIM + r] + gp * p;
    // S[t'][r] -> S2[256*(t'&7) + r][t'>>3]
    int trow = ((tp & 7) << 8) + r;
    int dcol = tp >> 3;
    S2[(size_t)trow * D_DIM + dcol] = Aval;
}

// ---------- K7: out = (x @ Wq) * S2, bf16 MFMA ----------
// Tile 128(M)x128(N), BK=64, 4 waves each computing 64x64 via 2x2 mfma_32x32x16.
// LDS fragment-ordered: chunk (s2h = k/8) of 128 rows x 8 bf16, 16B/lane reads.
__global__ __launch_bounds__(256) void k_qgemm_mfma(const float* __restrict__ x,
                                                    const ushort* __restrict__ WqT,
                                                    const float* __restrict__ S2,
                                                    float* __restrict__ out) {
    __shared__ ushort As[8 * 128 * 8];   // 16 KB
    __shared__ ushort Bs[8 * 128 * 8];   // 16 KB
    int bid = blockIdx.x;
    int mb = bid >> 1;           // 0..255  (M tile)
    int nb = bid & 1;            // 0..1    (N tile)
    int tid = threadIdx.x;
    int lane = tid & 63, w = tid >> 6;
    int wr = w >> 1, wc = w & 1;         // wave quadrant
    int l31 = lane & 31, lh = lane >> 5;

    f32x16 acc[2][2];
#pragma unroll
    for (int i = 0; i < 2; ++i)
#pragma unroll
        for (int j = 0; j < 2; ++j)
#pragma unroll
            for (int e = 0; e < 16; ++e) acc[i][j][e] = 0.f;

    int r = tid >> 1;            // 0..127 staging row
    int h0 = tid & 1;            // staging k-half (32 each)
    const float* xg = x + ((size_t)(mb * 128 + r)) * D_DIM + h0 * 32;
    const ushort* bg = WqT + ((size_t)(nb * 128 + r)) * D_DIM + h0 * 32;

    for (int kb = 0; kb < 4; ++kb) {
        // stage A (f32 -> bf16)
        const float4* xr4 = (const float4*)(xg + kb * 64);
#pragma unroll
        for (int j = 0; j < 8; ++j) {
            float4 v = xr4[j];
            int k = h0 * 32 + j * 4;
            int s2h = k >> 3;
            ushort4 pk;
            pk.x = f2bf(v.x); pk.y = f2bf(v.y); pk.z = f2bf(v.z); pk.w = f2bf(v.w);
            *(ushort4*)&As[(s2h * 128 + r) * 8 + (k & 7)] = pk;
        }
        // stage B (already bf16, [n][k] layout)
        const ushort* br = bg + kb * 64;
#pragma unroll
        for (int j = 0; j < 4; ++j) {
            bf16x8 v = *(const bf16x8*)(br + j * 8);
            int k = h0 * 32 + j * 8;
            int s2h = k >> 3;
            *(bf16x8*)&Bs[(s2h * 128 + r) * 8] = v;
        }
        __syncthreads();
#pragma unroll
        for (int s = 0; s < 4; ++s) {   // four K=16 steps
            int c0 = (s * 2 + lh) * 128;
            bf16x8 a0 = *(bf16x8*)&As[(c0 + wr * 64 + l31) * 8];
            bf16x8 a1 = *(bf16x8*)&As[(c0 + wr * 64 + 32 + l31) * 8];
            bf16x8 b0 = *(bf16x8*)&Bs[(c0 + wc * 64 + l31) * 8];
            bf16x8 b1 = *(bf16x8*)&Bs[(c0 + wc * 64 + 32 + l31) * 8];
            acc[0][0] = __builtin_amdgcn_mfma_f32_32x32x16_bf16(a0, b0, acc[0][0], 0, 0, 0);
            acc[0][1] = __builtin_amdgcn_mfma_f32_32x32x16_bf16(a0, b1, acc[0][1], 0, 0, 0);
            acc[1][0] = __builtin_amdgcn_mfma_f32_32x32x16_bf16(a1, b0, acc[1][0], 0, 0, 0);
            acc[1][1] = __builtin_amdgcn_mfma_f32_32x32x16_bf16(a1, b1, acc[1][1], 0, 0, 0);
        }
        __syncthreads();
    }

    // epilogue: out[gm][gn] = acc * S2[t][gn],  t = gm & 2047
    int t_base = (mb & 15) * 128;
    size_t row_base = (size_t)mb * 128;
#pragma unroll
    for (int mi = 0; mi < 2; ++mi) {
#pragma unroll
        for (int ni = 0; ni < 2; ++ni) {
            int gn = nb * 128 + wc * 64 + ni * 32 + l31;
#pragma unroll
            for (int reg = 0; reg < 16; ++reg) {
                int rr = (reg & 3) + 8 * (reg >> 2) + 4 * lh;
                int m = wr * 64 + mi * 32 + rr;
                float s2v = S2[(size_t)(t_base + m) * D_DIM + gn];
                out[(row_base + m) * D_DIM + gn] = acc[mi][ni][reg] * s2v;
            }
        }
    }
}

extern "C" void kernel_launch(void* const* d_in, const int* in_sizes, int n_in,
                              void* d_out, int out_size, void* d_ws, size_t ws_size,
                              hipStream_t stream) {
    const float* x  = (const float*)d_in[0];
    const float* Wq = (const float*)d_in[1];
    const float* Wk = (const float*)d_in[2];
    const float* Wv = (const float*)d_in[3];
    float* out = (float*)d_out;

    // workspace layout (floats)
    float* ws = (float*)d_ws;
    float* y      = ws;                       // 2048*256
    float* g      = y + 524288;               // 2048*256
    float* loc    = g + 524288;               // 2048*256
    float* S2     = loc + 524288;             // 2048*256
    float* wv_sum = S2 + 524288;              // 256
    float* carry  = wv_sum + 256;             // 32*256
    ushort* WqT   = (ushort*)(carry + 8192);  // 256*256 bf16 (32768 floats worth)

    k_wvsum<<<256, 64, 0, stream>>>(Wv, wv_sum);
    k_wqT<<<16, 256, 0, stream>>>(Wq, WqT);
    k_y<<<T_LEN, 256, 0, stream>>>(x, wv_sum, y);
    k_g<<<T_LEN / 8, 256, 0, stream>>>(y, Wk, g);
    k_scanA<<<NCHUNK, 256, 0, stream>>>(g, loc, carry);
    k_S2P<<<T_LEN, 256, 0, stream>>>(loc, carry, S2);
    k_qgemm_mfma<<<(B_DIM * T_LEN / 128) * 2, 256, 0, stream>>>(x, WqT, S2, out);
}

// Round 3
// 128.854 us; speedup vs baseline: 1.4444x; 1.1393x over previous
//
#include <hip/hip_runtime.h>
#include <hip/hip_bf16.h>
#include <math.h>

// Problem: B=16, T=2048, D=256, gamma=0.9
// out[b,t,d] = S2[t,d] * (x@Wq)[b,t,d]
// S2[t,d] = S[8d + (t>>8)][t&255]   (reshape-scramble)
// S[t>=1] = A[t], S[0] = A[1],  A[t] = gamma*A[t-1] + g[t], A[0]=0 (g[0] := 0)
// g = y @ Wk,  y[t,:] = sum_b w[b,t]*x[b,t,:],  w[b,t] = x[b,t,:] . rowsum(Wv)

#define GAMMA_F 0.9f
#define T_LEN 2048
#define D_DIM 256
#define B_DIM 16
#define NCHUNK 32
#define CHUNK 64

typedef __attribute__((ext_vector_type(8))) short bf16x8;
typedef __attribute__((ext_vector_type(16))) float f32x16;

__device__ inline ushort f2bf(float f) {
    union { float f; unsigned u; } v; v.f = f;
    unsigned r = (v.u + 0x7FFFu + ((v.u >> 16) & 1u)) >> 16;  // RNE
    return (ushort)r;
}

// ---------- K1: prep — WqT, WkT (bf16 [n][k]) + wv_sum ----------
__global__ __launch_bounds__(256) void k_prep(const float* __restrict__ Wq,
                                              const float* __restrict__ Wk,
                                              const float* __restrict__ Wv,
                                              ushort* __restrict__ WqT,
                                              ushort* __restrict__ WkT,
                                              float* __restrict__ wv_sum) {
    int bid = blockIdx.x;
    int tid = threadIdx.x;
    if (bid < 32) {
        __shared__ float tile[64][68];
        const float* W = (bid < 16) ? Wq : Wk;
        ushort* WT = (bid < 16) ? WqT : WkT;
        int b = bid & 15;
        int k0 = (b & 3) * 64;
        int n0 = (b >> 2) * 64;
        int r = tid >> 4;            // 0..15
        int c4 = (tid & 15) * 4;     // 0..60
#pragma unroll
        for (int i = 0; i < 4; ++i) {
            float4 v = *(const float4*)(W + (size_t)(k0 + r + 16 * i) * D_DIM + n0 + c4);
            *(float4*)&tile[r + 16 * i][c4] = v;
        }
        __syncthreads();
        int n = tid >> 2;            // 0..63
        int j0 = (tid & 3) * 16;     // 0..48
        ushort tmp[16];
#pragma unroll
        for (int i = 0; i < 16; ++i) tmp[i] = f2bf(tile[j0 + i][n]);
        ushort* dst = WT + (size_t)(n0 + n) * D_DIM + k0 + j0;
#pragma unroll
        for (int i = 0; i < 16; ++i) dst[i] = tmp[i];
    } else {
        // wv_sum: 4 blocks x 64 rows; 4 lanes per row
        int j = (bid - 32) * 64 + (tid >> 2);
        int q = tid & 3;
        const float4* row4 = (const float4*)(Wv + (size_t)j * D_DIM + q * 64);
        float s = 0.f;
#pragma unroll
        for (int i = 0; i < 16; ++i) {
            float4 v = row4[i];
            s += v.x + v.y + v.z + v.w;
        }
        s += __shfl_xor(s, 1, 64);
        s += __shfl_xor(s, 2, 64);
        if (q == 0) wv_sum[j] = s;
    }
}

// ---------- K2: y + xbf. Block per t. ----------
__global__ __launch_bounds__(256) void k_y(const float* __restrict__ x,
                                           const float* __restrict__ wv_sum,
                                           ushort* __restrict__ ybf,
                                           ushort* __restrict__ xbf) {
    int t = blockIdx.x;      // 0..2047
    int d = threadIdx.x;     // 0..255
    float wvd = wv_sum[d];
    float xr[B_DIM];
#pragma unroll
    for (int b = 0; b < B_DIM; ++b)
        xr[b] = x[((size_t)b * T_LEN + t) * D_DIM + d];
#pragma unroll
    for (int b = 0; b < B_DIM; ++b)
        xbf[((size_t)b * T_LEN + t) * D_DIM + d] = f2bf(xr[b]);

    __shared__ float red[B_DIM][4];
    int wave = d >> 6, lane = d & 63;
#pragma unroll
    for (int b = 0; b < B_DIM; ++b) {
        float p = xr[b] * wvd;
        for (int o = 32; o > 0; o >>= 1) p += __shfl_down(p, o, 64);
        if (lane == 0) red[b][wave] = p;
    }
    __syncthreads();
    float yv = 0.f;
#pragma unroll
    for (int b = 0; b < B_DIM; ++b) {
        float wb = red[b][0] + red[b][1] + red[b][2] + red[b][3];
        yv += wb * xr[b];
    }
    ybf[(size_t)t * D_DIM + d] = f2bf(yv);
}

// ---------- K3: g = ybf @ WkT^T  (bf16 MFMA, 64x64 tile) ----------
__global__ __launch_bounds__(256) void k_gmm(const ushort* __restrict__ ybf,
                                             const ushort* __restrict__ WkT,
                                             float* __restrict__ g) {
    __shared__ ushort As[32 * 64 * 8];   // 32 KB  [s2h][row^swz][8]
    __shared__ ushort Bs[32 * 64 * 8];   // 32 KB
    int mt = blockIdx.x >> 2;            // 0..31 (t tile)
    int nt = blockIdx.x & 3;             // 0..3  (n tile)
    int tid = threadIdx.x, lane = tid & 63, w = tid >> 6;
    int wr = w >> 1, wc = w & 1, l31 = lane & 31, lh = lane >> 5;

#pragma unroll
    for (int i = 0; i < 8; ++i) {
        int slot = tid + 256 * i;        // 0..2047
        int r = slot >> 5;               // 0..63
        int s2h = slot & 31;             // 0..31
        int rs = r ^ (s2h & 7);          // bank swizzle
        *(bf16x8*)&As[(s2h * 64 + rs) * 8] =
            *(const bf16x8*)&ybf[(size_t)(mt * 64 + r) * D_DIM + s2h * 8];
        *(bf16x8*)&Bs[(s2h * 64 + rs) * 8] =
            *(const bf16x8*)&WkT[(size_t)(nt * 64 + r) * D_DIM + s2h * 8];
    }
    __syncthreads();

    f32x16 acc;
#pragma unroll
    for (int e = 0; e < 16; ++e) acc[e] = 0.f;
#pragma unroll
    for (int s = 0; s < 16; ++s) {
        int s2h = s * 2 + lh;
        int ra = (wr * 32 + l31) ^ (s2h & 7);
        int rb = (wc * 32 + l31) ^ (s2h & 7);
        bf16x8 a = *(bf16x8*)&As[(s2h * 64 + ra) * 8];
        bf16x8 b = *(bf16x8*)&Bs[(s2h * 64 + rb) * 8];
        acc = __builtin_amdgcn_mfma_f32_32x32x16_bf16(a, b, acc, 0, 0, 0);
    }
#pragma unroll
    for (int reg = 0; reg < 16; ++reg) {
        int rr = (reg & 3) + 8 * (reg >> 2) + 4 * lh;
        g[(size_t)(mt * 64 + wr * 32 + rr) * D_DIM + nt * 64 + wc * 32 + l31] = acc[reg];
    }
}

// ---------- K4: per-chunk local scan ----------
__global__ void k_scanA(const float* __restrict__ g, float* __restrict__ loc,
                        float* __restrict__ carry) {
    int c = blockIdx.x;      // 0..31
    int d = threadIdx.x;     // 0..255
    float acc = 0.f;
    int base = c * CHUNK;
#pragma unroll
    for (int o8 = 0; o8 < 8; ++o8) {
        float v[8];
#pragma unroll
        for (int j = 0; j < 8; ++j) {
            int t = base + o8 * 8 + j;
            v[j] = (t == 0) ? 0.f : g[(size_t)t * D_DIM + d];
        }
#pragma unroll
        for (int j = 0; j < 8; ++j) {
            acc = GAMMA_F * acc + v[j];
            loc[(size_t)(base + o8 * 8 + j) * D_DIM + d] = acc;
        }
    }
    carry[(size_t)c * D_DIM + d] = acc;
}

// ---------- K5: A[t] = loc[t] + gamma^(o+1)*P[c]; P inline; scatter ----------
__global__ __launch_bounds__(256) void k_S2P(const float* __restrict__ loc,
                                             const float* __restrict__ carry,
                                             float* __restrict__ S2) {
    int tp = blockIdx.x;     // S row index t' = 0..2047
    int r = threadIdx.x;     // 0..255
    int src = (tp == 0) ? 1 : tp;           // S[0] = A[1]
    int c = src >> 6, o = src & 63;
    const float g64 = 1.1790184577738601e-03f;  // 0.9^64
    float p = 0.f;
    for (int j = 0; j < c; ++j)
        p = p * g64 + carry[(size_t)j * D_DIM + r];
    const float log2g = -0.15200309344504995f;  // log2(0.9)
    float gp = exp2f((float)(o + 1) * log2g);
    float Aval = loc[(size_t)src * D_DIM + r] + gp * p;
    // S[t'][r] -> S2[256*(t'&7) + r][t'>>3]
    int trow = ((tp & 7) << 8) + r;
    int dcol = tp >> 3;
    S2[(size_t)trow * D_DIM + dcol] = Aval;
}

// ---------- K6: out = (xbf @ WqT^T) * S2, bf16 MFMA, 128x128 tile ----------
__global__ __launch_bounds__(256) void k_qgemm(const ushort* __restrict__ xbf,
                                               const ushort* __restrict__ WqT,
                                               const float* __restrict__ S2,
                                               float* __restrict__ out) {
    __shared__ ushort As[8 * 128 * 8];   // 16 KB
    __shared__ ushort Bs[8 * 128 * 8];   // 16 KB
    int bid = blockIdx.x;
    int mb = bid >> 1;           // 0..255  (M tile)
    int nb = bid & 1;            // 0..1    (N tile)
    int tid = threadIdx.x;
    int lane = tid & 63, w = tid >> 6;
    int wr = w >> 1, wc = w & 1;
    int l31 = lane & 31, lh = lane >> 5;

    f32x16 acc[2][2];
#pragma unroll
    for (int i = 0; i < 2; ++i)
#pragma unroll
        for (int j = 0; j < 2; ++j)
#pragma unroll
            for (int e = 0; e < 16; ++e) acc[i][j][e] = 0.f;

    int r = tid >> 1;            // 0..127 staging row
    int h0 = tid & 1;            // k-half (32 each)
    const ushort* ag = xbf + (size_t)(mb * 128 + r) * D_DIM + h0 * 32;
    const ushort* bg = WqT + (size_t)(nb * 128 + r) * D_DIM + h0 * 32;

    for (int kb = 0; kb < 4; ++kb) {
#pragma unroll
        for (int j = 0; j < 4; ++j) {
            bf16x8 av = *(const bf16x8*)(ag + kb * 64 + j * 8);
            *(bf16x8*)&As[((h0 * 4 + j) * 128 + r) * 8] = av;
            bf16x8 bv = *(const bf16x8*)(bg + kb * 64 + j * 8);
            *(bf16x8*)&Bs[((h0 * 4 + j) * 128 + r) * 8] = bv;
        }
        __syncthreads();
#pragma unroll
        for (int s = 0; s < 4; ++s) {
            int c0 = (s * 2 + lh) * 128;
            bf16x8 a0 = *(bf16x8*)&As[(c0 + wr * 64 + l31) * 8];
            bf16x8 a1 = *(bf16x8*)&As[(c0 + wr * 64 + 32 + l31) * 8];
            bf16x8 b0 = *(bf16x8*)&Bs[(c0 + wc * 64 + l31) * 8];
            bf16x8 b1 = *(bf16x8*)&Bs[(c0 + wc * 64 + 32 + l31) * 8];
            acc[0][0] = __builtin_amdgcn_mfma_f32_32x32x16_bf16(a0, b0, acc[0][0], 0, 0, 0);
            acc[0][1] = __builtin_amdgcn_mfma_f32_32x32x16_bf16(a0, b1, acc[0][1], 0, 0, 0);
            acc[1][0] = __builtin_amdgcn_mfma_f32_32x32x16_bf16(a1, b0, acc[1][0], 0, 0, 0);
            acc[1][1] = __builtin_amdgcn_mfma_f32_32x32x16_bf16(a1, b1, acc[1][1], 0, 0, 0);
        }
        __syncthreads();
    }

    int t_base = (mb & 15) * 128;
    size_t row_base = (size_t)mb * 128;
#pragma unroll
    for (int mi = 0; mi < 2; ++mi) {
#pragma unroll
        for (int ni = 0; ni < 2; ++ni) {
            int gn = nb * 128 + wc * 64 + ni * 32 + l31;
#pragma unroll
            for (int reg = 0; reg < 16; ++reg) {
                int rr = (reg & 3) + 8 * (reg >> 2) + 4 * lh;
                int m = wr * 64 + mi * 32 + rr;
                float s2v = S2[(size_t)(t_base + m) * D_DIM + gn];
                out[(row_base + m) * D_DIM + gn] = acc[mi][ni][reg] * s2v;
            }
        }
    }
}

extern "C" void kernel_launch(void* const* d_in, const int* in_sizes, int n_in,
                              void* d_out, int out_size, void* d_ws, size_t ws_size,
                              hipStream_t stream) {
    const float* x  = (const float*)d_in[0];
    const float* Wq = (const float*)d_in[1];
    const float* Wk = (const float*)d_in[2];
    const float* Wv = (const float*)d_in[3];
    float* out = (float*)d_out;

    // workspace layout (float units; every piece is a multiple of 256 floats)
    float* ws = (float*)d_ws;
    float* g      = ws;                        // 524288
    float* loc    = g + 524288;                // 524288
    float* S2     = loc + 524288;              // 524288
    float* wv_sum = S2 + 524288;               // 256
    float* carry  = wv_sum + 256;              // 8192
    ushort* WqT   = (ushort*)(carry + 8192);   // 65536 ushort
    ushort* WkT   = WqT + 65536;               // 65536 ushort
    ushort* ybf   = WkT + 65536;               // 524288 ushort
    ushort* xbf   = ybf + 524288;              // 8388608 ushort

    k_prep<<<36, 256, 0, stream>>>(Wq, Wk, Wv, WqT, WkT, wv_sum);
    k_y<<<T_LEN, 256, 0, stream>>>(x, wv_sum, ybf, xbf);
    k_gmm<<<128, 256, 0, stream>>>(ybf, WkT, g);
    k_scanA<<<NCHUNK, 256, 0, stream>>>(g, loc, carry);
    k_S2P<<<T_LEN, 256, 0, stream>>>(loc, carry, S2);
    k_qgemm<<<(B_DIM * T_LEN / 128) * 2, 256, 0, stream>>>(xbf, WqT, S2, out);
}